// Round 3
// baseline (158.293 us; speedup 1.0000x reference)
//
#include <hip/hip_runtime.h>
#include <math.h>

// Problem constants (from reference): B=2048, P_ROWS=128, N=64, Q=8
#define NB    2048
#define PROWS 128
#define NDIM  64
#define QCNT  8

// One block per batch (256 threads = 4 waves). Memory-bound streaming of
// A1 (32KB) + P (128KB) per batch.
// Structure: wave w owns q in {2w, 2w+1}; each lane accumulates 3 bilinear
// scalars for its fixed column-float4 -> zero syncs in the hot loop, one
// 6-level butterfly per q. Low register pressure keeps 16+ waves/CU.
// Norm trick: out = z0 + min(1/kraw,1)*v with kraw from raw v (||v|| cancels).
__global__ __launch_bounds__(256, 4) void constraint_kernel(
    const float* __restrict__ v,    // (B, 64)
    const float* __restrict__ A1,   // (B, 128, 64)
    const float* __restrict__ b1,   // (B, 128)
    const float* __restrict__ z0,   // (B, 64)
    const float* __restrict__ P,    // (B, 8, 64, 64)
    const float* __restrict__ qv,   // (B, 8, 64)
    const float* __restrict__ rr,   // (B, 8)
    float* __restrict__ out)        // (B, 64)
{
    const int b    = blockIdx.x;
    const int tid  = threadIdx.x;
    const int lane = tid & 63;
    const int w    = tid >> 6;

    __shared__ __align__(16) float s_v[NDIM];
    __shared__ __align__(16) float s_z[NDIM];
    __shared__ float s_lin[4];
    __shared__ float s_kq[4];
    __shared__ float s_beta;

    if (tid < NDIM) {
        s_v[tid] = v[b * NDIM + tid];
        s_z[tid] = z0[b * NDIM + tid];
    }
    __syncthreads();

    // ---------- Phase B: A1 dots. thread = (rg = tid>>2, s4 = tid&3) ----------
    // row = pass*64 + rg; cols s4*16 .. s4*16+15 (4 consecutive float4).
    const int rg = tid >> 2;
    const int s4 = tid & 3;
    const float* A1b = A1 + (size_t)b * PROWS * NDIM;
    float dvb[2], dzb[2];
    {
        float4 vB[4], zB[4];
        #pragma unroll
        for (int k = 0; k < 4; ++k) {
            vB[k] = *(const float4*)&s_v[s4 * 16 + k * 4];
            zB[k] = *(const float4*)&s_z[s4 * 16 + k * 4];
        }
        #pragma unroll
        for (int pass = 0; pass < 2; ++pass) {
            const float* rowp = A1b + (pass * 64 + rg) * NDIM + s4 * 16;
            float dv = 0.f, dz = 0.f;
            #pragma unroll
            for (int k = 0; k < 4; ++k) {
                const float4 a = *(const float4*)&rowp[k * 4];
                dv += a.x * vB[k].x + a.y * vB[k].y + a.z * vB[k].z + a.w * vB[k].w;
                dz += a.x * zB[k].x + a.y * zB[k].y + a.z * zB[k].z + a.w * zB[k].w;
            }
            dvb[pass] = dv;
            dzb[pass] = dz;
        }
    }

    // ---------- Phase C: wave w owns q = 2w, 2w+1 ----------
    // lane = (r0 = lane>>4 in [0,4), cg = lane&15); lane's column float4 =
    // cols cg*4..cg*4+3; rows r0+4k, k=0..15. Wave load = 1KB contiguous.
    const int cg = lane & 15;
    const int r0 = lane >> 4;
    const float4 v4 = *(const float4*)&s_v[cg * 4];
    const float4 z4 = *(const float4*)&s_z[cg * 4];

    float kqw = 0.f;  // kq >= 0 always (PSD => sqrt(quad) >= |gv/sigma|)
    #pragma unroll
    for (int qi = 0; qi < 2; ++qi) {
        const int qq = w * 2 + qi;
        const float* Pq = P + ((size_t)b * QCNT + qq) * (NDIM * NDIM) + cg * 4;
        float a0 = 0.f, a1 = 0.f, a2 = 0.f, a3 = 0.f;
        #pragma unroll
        for (int k = 0; k < 16; ++k) {
            const int r = r0 + k * 4;
            const float4 p4 = *(const float4*)&Pq[r * NDIM];
            const float dpv = p4.x * v4.x + p4.y * v4.y + p4.z * v4.z + p4.w * v4.w;
            const float dpz = p4.x * z4.x + p4.y * z4.y + p4.z * z4.z + p4.w * z4.w;
            const float vr = s_v[r];
            const float zr = s_z[r];
            a0 += vr * dpv;   // -> v^T P v
            a1 += vr * dpz;   // -> v^T P z0
            a2 += zr * dpz;   // -> z0^T P z0
        }
        if (r0 == 0) {  // 16 lanes cover the q vector once
            const float4 q4 = *(const float4*)&qv[((size_t)b * QCNT + qq) * NDIM + cg * 4];
            a1 += q4.x * v4.x + q4.y * v4.y + q4.z * v4.z + q4.w * v4.w;  // + q.v
            a3  = q4.x * z4.x + q4.y * z4.y + q4.z * z4.z + q4.w * z4.w;  // q.z0
        }
        #pragma unroll
        for (int m = 32; m >= 1; m >>= 1) {
            a0 += __shfl_xor(a0, m);
            a1 += __shfl_xor(a1, m);
            a2 += __shfl_xor(a2, m);
            a3 += __shfl_xor(a3, m);
        }
        // all lanes now hold the full sums; a1 = g.v, a0 = vPv
        const float c0    = 0.5f * a2 + a3 + rr[b * QCNT + qq];
        const float sigma = 2.f * c0;
        const float quad  = (a1 * a1 - 2.f * c0 * a0) / (sigma * sigma);
        const float kq    = -a1 / sigma + sqrtf(quad);
        kqw = fmaxf(kqw, kq);
    }

    // ---------- Phase B reduce: 4-lane groups ----------
    float lmax = -INFINITY;
    #pragma unroll
    for (int pass = 0; pass < 2; ++pass) {
        float dv = dvb[pass], dz = dzb[pass];
        dv += __shfl_xor(dv, 1); dv += __shfl_xor(dv, 2);
        dz += __shfl_xor(dz, 1); dz += __shfl_xor(dz, 2);
        if (s4 == 0) {
            const float denom = b1[b * PROWS + pass * 64 + rg] - dz;  // > 0
            lmax = fmaxf(lmax, dv / denom);
        }
    }
    #pragma unroll
    for (int m = 32; m >= 1; m >>= 1) lmax = fmaxf(lmax, __shfl_xor(lmax, m));

    if (lane == 0) {
        s_lin[w] = lmax;
        s_kq[w]  = kqw;
    }
    __syncthreads();
    if (tid == 0) {
        const float klin = fmaxf(fmaxf(s_lin[0], s_lin[1]), fmaxf(s_lin[2], s_lin[3]));
        const float kqm  = fmaxf(fmaxf(s_kq[0], s_kq[1]), fmaxf(s_kq[2], s_kq[3]));
        const float kraw = fmaxf(fmaxf(klin, 0.f), kqm);
        s_beta = fminf(1.f / kraw, 1.f);  // 1/0 = inf -> 1 (alpha = ||v||)
    }
    __syncthreads();
    if (tid < NDIM) {
        out[b * NDIM + tid] = s_z[tid] + s_beta * s_v[tid];
    }
}

extern "C" void kernel_launch(void* const* d_in, const int* in_sizes, int n_in,
                              void* d_out, int out_size, void* d_ws, size_t ws_size,
                              hipStream_t stream) {
    const float* v  = (const float*)d_in[0];
    const float* A1 = (const float*)d_in[1];
    const float* b1 = (const float*)d_in[2];
    const float* z0 = (const float*)d_in[3];
    const float* P  = (const float*)d_in[4];
    const float* qv = (const float*)d_in[5];
    const float* rr = (const float*)d_in[6];
    float* out = (float*)d_out;

    constraint_kernel<<<NB, 256, 0, stream>>>(v, A1, b1, z0, P, qv, rr, out);
}

// Round 4
// 78.437 us; speedup vs baseline: 2.0181x; 2.0181x over previous
//
#include <hip/hip_runtime.h>
#include <math.h>

// Problem constants (from reference): B=2048, P_ROWS=128, N=64, Q=8
#define NB    2048
#define PROWS 128
#define NDIM  64
#define QCNT  8

// One block per batch (256 threads = 4 waves). Memory-bound streaming of
// A1 (32KB) + P (128KB) per batch. R1 structure (proven 78.8us) minus its
// waste: no norm phase (||v|| cancels into beta), no syncs inside the q-loop
// (per-wave butterfly -> s_red, single final sync).
// NO launch_bounds VGPR cap: compiler needs registers to keep ~16 loads in
// flight per thread (R3 proved capping to 64 VGPRs -> 1.7 TB/s latency-bound).
__global__ __launch_bounds__(256) void constraint_kernel(
    const float* __restrict__ v,    // (B, 64)
    const float* __restrict__ A1,   // (B, 128, 64)
    const float* __restrict__ b1,   // (B, 128)
    const float* __restrict__ z0,   // (B, 64)
    const float* __restrict__ P,    // (B, 8, 64, 64)
    const float* __restrict__ qv,   // (B, 8, 64)
    const float* __restrict__ rr,   // (B, 8)
    float* __restrict__ out)        // (B, 64)
{
    const int b    = blockIdx.x;
    const int tid  = threadIdx.x;
    const int lane = tid & 63;
    const int w    = tid >> 6;

    __shared__ __align__(16) float s_v[NDIM];
    __shared__ __align__(16) float s_z[NDIM];
    __shared__ float s_red[4][QCNT][4];  // wave, q, {vPv, g.v, zPz, q.z}
    __shared__ float s_lin[4];
    __shared__ float s_beta;

    if (tid < NDIM) {
        s_v[tid] = v[b * NDIM + tid];
        s_z[tid] = z0[b * NDIM + tid];
    }
    __syncthreads();

    // ---------- Phase B: linear rows (R1 mapping: 16 threads/row) ----------
    const int sub = tid & 15;   // column chunk
    const int grp = tid >> 4;   // row group
    const float4 vB = *(const float4*)&s_v[sub * 4];
    const float4 zB = *(const float4*)&s_z[sub * 4];
    float lmax = -INFINITY;
    const float* A1b = A1 + (size_t)b * PROWS * NDIM;
    #pragma unroll
    for (int p = 0; p < 8; ++p) {
        const float4 a = *(const float4*)&A1b[(p * 16 + grp) * NDIM + sub * 4];
        float dv = a.x * vB.x + a.y * vB.y + a.z * vB.z + a.w * vB.w;
        float dz = a.x * zB.x + a.y * zB.y + a.z * zB.z + a.w * zB.w;
        #pragma unroll
        for (int m = 8; m >= 1; m >>= 1) {
            dv += __shfl_xor(dv, m);
            dz += __shfl_xor(dz, m);
        }
        if (sub == 0) {
            const float denom = b1[b * PROWS + p * 16 + grp] - dz;  // > 0
            lmax = fmaxf(lmax, dv / denom);
        }
    }
    #pragma unroll
    for (int m = 32; m >= 1; m >>= 1) lmax = fmaxf(lmax, __shfl_xor(lmax, m));
    if (lane == 0) s_lin[w] = lmax;

    // ---------- Phase C: quadratic bilinear partials (R1 mapping) ----------
    // thread = (i = tid>>2 row, s4 = tid&3); cols {k*16 + s4*4 .. +3}, k=0..3.
    const int i  = tid >> 2;
    const int s4 = tid & 3;
    const float vi = s_v[i];
    const float zi = s_z[i];
    float4 vj[4], zj[4];
    #pragma unroll
    for (int k = 0; k < 4; ++k) {
        vj[k] = *(const float4*)&s_v[k * 16 + s4 * 4];
        zj[k] = *(const float4*)&s_z[k * 16 + s4 * 4];
    }

    const float* Pb = P + (size_t)b * QCNT * NDIM * NDIM + i * NDIM;
    #pragma unroll
    for (int qq = 0; qq < QCNT; ++qq) {
        const float* Pq = Pb + qq * NDIM * NDIM;
        float dr = 0.f, dy = 0.f;
        #pragma unroll
        for (int k = 0; k < 4; ++k) {
            const float4 p4 = *(const float4*)&Pq[k * 16 + s4 * 4];
            dr += p4.x * vj[k].x + p4.y * vj[k].y + p4.z * vj[k].z + p4.w * vj[k].w;
            dy += p4.x * zj[k].x + p4.y * zj[k].y + p4.z * zj[k].z + p4.w * zj[k].w;
        }
        float a0 = vi * dr;   // -> v^T P v
        float a1 = vi * dy;   // -> v^T P z0 (part of g.v)
        float a2 = zi * dy;   // -> z0^T P z0
        float a3 = 0.f;       // -> q.z0
        if (s4 == 0) {
            const float qvi = qv[(size_t)b * QCNT * NDIM + qq * NDIM + i];
            a1 += qvi * vi;   // + q.v completes g.v
            a3  = qvi * zi;
        }
        #pragma unroll
        for (int m = 32; m >= 1; m >>= 1) {
            a0 += __shfl_xor(a0, m);
            a1 += __shfl_xor(a1, m);
            a2 += __shfl_xor(a2, m);
            a3 += __shfl_xor(a3, m);
        }
        if (lane == 0) {
            s_red[w][qq][0] = a0; s_red[w][qq][1] = a1;
            s_red[w][qq][2] = a2; s_red[w][qq][3] = a3;
        }
    }
    __syncthreads();

    // ---------- Final: 8 lanes, one q each ----------
    float kq = -INFINITY;
    if (tid < QCNT) {
        const float vPv = s_red[0][tid][0] + s_red[1][tid][0] + s_red[2][tid][0] + s_red[3][tid][0];
        const float gvw = s_red[0][tid][1] + s_red[1][tid][1] + s_red[2][tid][1] + s_red[3][tid][1];
        const float zPz = s_red[0][tid][2] + s_red[1][tid][2] + s_red[2][tid][2] + s_red[3][tid][2];
        const float qz  = s_red[0][tid][3] + s_red[1][tid][3] + s_red[2][tid][3] + s_red[3][tid][3];
        const float c0    = 0.5f * zPz + qz + rr[b * QCNT + tid];
        const float sigma = 2.f * c0;
        const float quad  = (gvw * gvw - 2.f * c0 * vPv) / (sigma * sigma);
        kq = -gvw / sigma + sqrtf(quad);
    }
    #pragma unroll
    for (int m = 4; m >= 1; m >>= 1) kq = fmaxf(kq, __shfl_xor(kq, m));
    if (tid == 0) {
        const float klin = fmaxf(fmaxf(s_lin[0], s_lin[1]), fmaxf(s_lin[2], s_lin[3]));
        const float kraw = fmaxf(fmaxf(klin, 0.f), kq);
        s_beta = fminf(1.f / kraw, 1.f);  // 1/0 = inf -> 1 (alpha = ||v||)
    }
    __syncthreads();
    if (tid < NDIM) {
        out[b * NDIM + tid] = s_z[tid] + s_beta * s_v[tid];
    }
}

extern "C" void kernel_launch(void* const* d_in, const int* in_sizes, int n_in,
                              void* d_out, int out_size, void* d_ws, size_t ws_size,
                              hipStream_t stream) {
    const float* v  = (const float*)d_in[0];
    const float* A1 = (const float*)d_in[1];
    const float* b1 = (const float*)d_in[2];
    const float* z0 = (const float*)d_in[3];
    const float* P  = (const float*)d_in[4];
    const float* qv = (const float*)d_in[5];
    const float* rr = (const float*)d_in[6];
    float* out = (float*)d_out;

    constraint_kernel<<<NB, 256, 0, stream>>>(v, A1, b1, z0, P, qv, rr, out);
}

// Round 5
// 70.579 us; speedup vs baseline: 2.2428x; 1.1113x over previous
//
#include <hip/hip_runtime.h>
#include <math.h>

// Problem constants (from reference): B=2048, P_ROWS=128, N=64, Q=8
#define NB    2048
#define PROWS 128
#define NDIM  64
#define QCNT  8

// Decoupled design: 10240 independent 32KB-streaming blocks.
//   blocks [0, 8192):  quad role  — (batch b = bid>>2, q-pair p2 = bid&3),
//                      streams 2 P-slices (32KB), writes ws[b*8 + p2].
//   blocks [8192, ..): linear role — batch b, streams A1 (32KB),
//                      writes ws[b*8 + 4].
// 40 blocks/CU queued -> reduce tails of finishing blocks overlap load
// phases of fresh blocks (R4 had exactly one round of 8 blocks/CU, so the
// synchronized shuffle-reduce tails were uncovered).
// Norm trick: out = z0 + min(1/kraw,1)*v with kraw from raw v (||v|| cancels).
__global__ __launch_bounds__(256) void main_kernel(
    const float* __restrict__ v,    // (B, 64)
    const float* __restrict__ A1,   // (B, 128, 64)
    const float* __restrict__ b1,   // (B, 128)
    const float* __restrict__ z0,   // (B, 64)
    const float* __restrict__ P,    // (B, 8, 64, 64)
    const float* __restrict__ qv,   // (B, 8, 64)
    const float* __restrict__ rr,   // (B, 8)
    float* __restrict__ ws)         // (B, 8) kappa slots
{
    const int bid  = blockIdx.x;
    const int tid  = threadIdx.x;
    const int lane = tid & 63;
    const int w    = tid >> 6;

    __shared__ __align__(16) float s_v[NDIM];
    __shared__ __align__(16) float s_z[NDIM];
    __shared__ float s_red[4][2][4];
    __shared__ float s_lin[4];

    if (bid < NB * 4) {
        // ================= QUAD ROLE =================
        const int b  = bid >> 2;
        const int p2 = bid & 3;

        if (tid < NDIM) {
            s_v[tid] = v[b * NDIM + tid];
            s_z[tid] = z0[b * NDIM + tid];
        }
        __syncthreads();

        // thread = (row i = tid>>2, col chunk s4 = tid&3); cols {k*16+s4*4..+3}
        const int i  = tid >> 2;
        const int s4 = tid & 3;
        const float vi = s_v[i];
        const float zi = s_z[i];
        float4 vj[4], zj[4];
        #pragma unroll
        for (int k = 0; k < 4; ++k) {
            vj[k] = *(const float4*)&s_v[k * 16 + s4 * 4];
            zj[k] = *(const float4*)&s_z[k * 16 + s4 * 4];
        }

        #pragma unroll
        for (int qi = 0; qi < 2; ++qi) {
            const int qq = p2 * 2 + qi;
            const float* Pq = P + ((size_t)b * QCNT + qq) * (NDIM * NDIM) + i * NDIM;
            float dr = 0.f, dy = 0.f;
            #pragma unroll
            for (int k = 0; k < 4; ++k) {
                const float4 p4 = *(const float4*)&Pq[k * 16 + s4 * 4];
                dr += p4.x * vj[k].x + p4.y * vj[k].y + p4.z * vj[k].z + p4.w * vj[k].w;
                dy += p4.x * zj[k].x + p4.y * zj[k].y + p4.z * zj[k].z + p4.w * zj[k].w;
            }
            float a0 = vi * dr;   // -> v^T P v
            float a1 = vi * dy;   // -> v^T P z0 (part of g.v)
            float a2 = zi * dy;   // -> z0^T P z0
            float a3 = 0.f;       // -> q.z0
            if (s4 == 0) {
                const float qvi = qv[((size_t)b * QCNT + qq) * NDIM + i];
                a1 += qvi * vi;   // + q.v completes g.v
                a3  = qvi * zi;
            }
            #pragma unroll
            for (int m = 32; m >= 1; m >>= 1) {
                a0 += __shfl_xor(a0, m);
                a1 += __shfl_xor(a1, m);
                a2 += __shfl_xor(a2, m);
                a3 += __shfl_xor(a3, m);
            }
            if (lane == 0) {
                s_red[w][qi][0] = a0; s_red[w][qi][1] = a1;
                s_red[w][qi][2] = a2; s_red[w][qi][3] = a3;
            }
        }
        __syncthreads();

        float kq = 0.f;
        if (tid < 2) {  // tid == qi
            const float vPv = s_red[0][tid][0] + s_red[1][tid][0] + s_red[2][tid][0] + s_red[3][tid][0];
            const float gvw = s_red[0][tid][1] + s_red[1][tid][1] + s_red[2][tid][1] + s_red[3][tid][1];
            const float zPz = s_red[0][tid][2] + s_red[1][tid][2] + s_red[2][tid][2] + s_red[3][tid][2];
            const float qz  = s_red[0][tid][3] + s_red[1][tid][3] + s_red[2][tid][3] + s_red[3][tid][3];
            const float c0    = 0.5f * zPz + qz + rr[b * QCNT + p2 * 2 + tid];
            const float sigma = 2.f * c0;
            const float quad  = (gvw * gvw - 2.f * c0 * vPv) / (sigma * sigma);
            kq = -gvw / sigma + sqrtf(quad);   // >= 0 (PSD)
        }
        const float kq_other = __shfl_xor(kq, 1);
        if (tid == 0) ws[b * 8 + p2] = fmaxf(kq, kq_other);

    } else {
        // ================= LINEAR ROLE =================
        const int b = bid - NB * 4;

        if (tid < NDIM) {
            s_v[tid] = v[b * NDIM + tid];
            s_z[tid] = z0[b * NDIM + tid];
        }
        __syncthreads();

        const int sub = tid & 15;   // column chunk
        const int grp = tid >> 4;   // row group
        const float4 vB = *(const float4*)&s_v[sub * 4];
        const float4 zB = *(const float4*)&s_z[sub * 4];
        float lmax = -INFINITY;
        const float* A1b = A1 + (size_t)b * PROWS * NDIM;
        #pragma unroll
        for (int p = 0; p < 8; ++p) {
            const float4 a = *(const float4*)&A1b[(p * 16 + grp) * NDIM + sub * 4];
            float dv = a.x * vB.x + a.y * vB.y + a.z * vB.z + a.w * vB.w;
            float dz = a.x * zB.x + a.y * zB.y + a.z * zB.z + a.w * zB.w;
            #pragma unroll
            for (int m = 8; m >= 1; m >>= 1) {
                dv += __shfl_xor(dv, m);
                dz += __shfl_xor(dz, m);
            }
            if (sub == 0) {
                const float denom = b1[b * PROWS + p * 16 + grp] - dz;  // > 0
                lmax = fmaxf(lmax, dv / denom);
            }
        }
        #pragma unroll
        for (int m = 32; m >= 1; m >>= 1) lmax = fmaxf(lmax, __shfl_xor(lmax, m));
        if (lane == 0) s_lin[w] = lmax;
        __syncthreads();
        if (tid == 0) {
            const float km = fmaxf(fmaxf(s_lin[0], s_lin[1]), fmaxf(s_lin[2], s_lin[3]));
            ws[b * 8 + 4] = fmaxf(km, 0.f);  // relu
        }
    }
}

// out = z0 + min(1/kraw, 1) * v, kraw = max of 5 ws slots per batch.
__global__ __launch_bounds__(256) void finalize_kernel(
    const float* __restrict__ v,
    const float* __restrict__ z0,
    const float* __restrict__ ws,
    float* __restrict__ out)
{
    const int idx = blockIdx.x * 256 + threadIdx.x;  // over B*64
    const int b   = idx >> 6;
    const float k0 = ws[b * 8 + 0];
    const float k1 = ws[b * 8 + 1];
    const float k2 = ws[b * 8 + 2];
    const float k3 = ws[b * 8 + 3];
    const float k4 = ws[b * 8 + 4];
    const float kraw = fmaxf(fmaxf(fmaxf(k0, k1), fmaxf(k2, k3)), k4);
    const float beta = fminf(1.f / kraw, 1.f);  // 1/0 = inf -> 1
    out[idx] = z0[idx] + beta * v[idx];
}

extern "C" void kernel_launch(void* const* d_in, const int* in_sizes, int n_in,
                              void* d_out, int out_size, void* d_ws, size_t ws_size,
                              hipStream_t stream) {
    const float* v  = (const float*)d_in[0];
    const float* A1 = (const float*)d_in[1];
    const float* b1 = (const float*)d_in[2];
    const float* z0 = (const float*)d_in[3];
    const float* P  = (const float*)d_in[4];
    const float* qv = (const float*)d_in[5];
    const float* rr = (const float*)d_in[6];
    float* ws  = (float*)d_ws;   // B*8 floats = 64KB
    float* out = (float*)d_out;

    main_kernel<<<NB * 4 + NB, 256, 0, stream>>>(v, A1, b1, z0, P, qv, rr, ws);
    finalize_kernel<<<(NB * NDIM) / 256, 256, 0, stream>>>(v, z0, ws, out);
}

// Round 6
// 53.572 us; speedup vs baseline: 2.9548x; 1.3174x over previous
//
#include <hip/hip_runtime.h>
#include <math.h>

// Problem constants (from reference): B=2048, P_ROWS=128, N=64, Q=8
#define NB    2048
#define PROWS 128
#define NDIM  64
#define QCNT  8

// Decoupled design (R5, 4.87 TB/s) + symmetric-P traffic cut:
// P is bitwise symmetric (P = G G^T / N, einsum computes P_ij and P_ji as the
// identical k-reduction). View P as [[A,B],[B^T,C]] (32x32 blocks) and read
// only A, B, C  => 12KB instead of 16KB per (b,q) slice. Each 32x32 block row
// is one 128B L2 line, 8 lanes per row -> fetched lines fully used.
//   v'Pv = vu'Avu + 2 vu'Bvl + vl'Cvl
//   v'Pz = vu'Azu + (vu'Bzl + zu'Bvl) + vl'Czl
//   z'Pz = zu'Azu + 2 zu'Bzl + zl'Czl
// blocks [0, 8192):  quad role  — (b = bid>>2, q-pair = bid&3), 24KB stream
// blocks [8192, ..): linear role — batch b, streams A1 (32KB)
// Norm trick: out = z0 + min(1/kraw,1)*v with kraw from raw v (||v|| cancels).
__global__ __launch_bounds__(256) void main_kernel(
    const float* __restrict__ v,    // (B, 64)
    const float* __restrict__ A1,   // (B, 128, 64)
    const float* __restrict__ b1,   // (B, 128)
    const float* __restrict__ z0,   // (B, 64)
    const float* __restrict__ P,    // (B, 8, 64, 64)
    const float* __restrict__ qv,   // (B, 8, 64)
    const float* __restrict__ rr,   // (B, 8)
    float* __restrict__ ws)         // (B, 8) kappa slots
{
    const int bid  = blockIdx.x;
    const int tid  = threadIdx.x;
    const int lane = tid & 63;
    const int w    = tid >> 6;

    __shared__ __align__(16) float s_v[NDIM];
    __shared__ __align__(16) float s_z[NDIM];
    __shared__ float s_red[4][2][4];
    __shared__ float s_lin[4];

    if (bid < NB * 4) {
        // ================= QUAD ROLE =================
        const int b  = bid >> 2;
        const int p2 = bid & 3;

        if (tid < NDIM) {
            s_v[tid] = v[b * NDIM + tid];
            s_z[tid] = z0[b * NDIM + tid];
        }
        __syncthreads();

        // thread = (row i = tid>>3 in [0,32), chunk j4 = tid&7)
        const int i  = tid >> 3;
        const int j4 = tid & 7;
        const float4 vu = *(const float4*)&s_v[j4 * 4];        // cols j4*4 (upper)
        const float4 vl = *(const float4*)&s_v[32 + j4 * 4];   // cols 32+j4*4 (lower)
        const float4 zu = *(const float4*)&s_z[j4 * 4];
        const float4 zl = *(const float4*)&s_z[32 + j4 * 4];
        const float vi_u = s_v[i];
        const float vi_l = s_v[32 + i];
        const float zi_u = s_z[i];
        const float zi_l = s_z[32 + i];

        #pragma unroll
        for (int qi = 0; qi < 2; ++qi) {
            const int qq = p2 * 2 + qi;
            const float* Pq = P + ((size_t)b * QCNT + qq) * (NDIM * NDIM);
            // A: rows 0-31, cols 0-31 ; B: rows 0-31, cols 32-63 ;
            // C: rows 32-63, cols 32-63  (skip B^T: rows 32-63, cols 0-31)
            const float4 pA = *(const float4*)&Pq[i * NDIM + j4 * 4];
            const float4 pB = *(const float4*)&Pq[i * NDIM + 32 + j4 * 4];
            const float4 pC = *(const float4*)&Pq[(32 + i) * NDIM + 32 + j4 * 4];

            const float dAv = pA.x * vu.x + pA.y * vu.y + pA.z * vu.z + pA.w * vu.w;
            const float dAz = pA.x * zu.x + pA.y * zu.y + pA.z * zu.z + pA.w * zu.w;
            const float dBv = pB.x * vl.x + pB.y * vl.y + pB.z * vl.z + pB.w * vl.w;
            const float dBz = pB.x * zl.x + pB.y * zl.y + pB.z * zl.z + pB.w * zl.w;
            const float dCv = pC.x * vl.x + pC.y * vl.y + pC.z * vl.z + pC.w * vl.w;
            const float dCz = pC.x * zl.x + pC.y * zl.y + pC.z * zl.z + pC.w * zl.w;

            float a0 = vi_u * dAv + 2.f * vi_u * dBv + vi_l * dCv;            // v'Pv
            float a1 = vi_u * dAz + vi_u * dBz + zi_u * dBv + vi_l * dCz;     // v'Pz0
            float a2 = zi_u * dAz + 2.f * zi_u * dBz + zi_l * dCz;            // z0'Pz0
            float a3 = 0.f;                                                   // q.z0
            if (tid < 16) {  // 16 threads cover the q vector once
                const float4 q4 = *(const float4*)&qv[((size_t)b * QCNT + qq) * NDIM + tid * 4];
                const float4 vq = *(const float4*)&s_v[tid * 4];
                const float4 zq = *(const float4*)&s_z[tid * 4];
                a1 += q4.x * vq.x + q4.y * vq.y + q4.z * vq.z + q4.w * vq.w;  // + q.v
                a3  = q4.x * zq.x + q4.y * zq.y + q4.z * zq.z + q4.w * zq.w;  // q.z0
            }
            #pragma unroll
            for (int m = 32; m >= 1; m >>= 1) {
                a0 += __shfl_xor(a0, m);
                a1 += __shfl_xor(a1, m);
                a2 += __shfl_xor(a2, m);
                a3 += __shfl_xor(a3, m);
            }
            if (lane == 0) {
                s_red[w][qi][0] = a0; s_red[w][qi][1] = a1;
                s_red[w][qi][2] = a2; s_red[w][qi][3] = a3;
            }
        }
        __syncthreads();

        float kq = 0.f;
        if (tid < 2) {  // tid == qi
            const float vPv = s_red[0][tid][0] + s_red[1][tid][0] + s_red[2][tid][0] + s_red[3][tid][0];
            const float gvw = s_red[0][tid][1] + s_red[1][tid][1] + s_red[2][tid][1] + s_red[3][tid][1];
            const float zPz = s_red[0][tid][2] + s_red[1][tid][2] + s_red[2][tid][2] + s_red[3][tid][2];
            const float qz  = s_red[0][tid][3] + s_red[1][tid][3] + s_red[2][tid][3] + s_red[3][tid][3];
            const float c0    = 0.5f * zPz + qz + rr[b * QCNT + p2 * 2 + tid];
            const float sigma = 2.f * c0;
            const float quad  = (gvw * gvw - 2.f * c0 * vPv) / (sigma * sigma);
            kq = -gvw / sigma + sqrtf(quad);   // >= 0 (PSD)
        }
        const float kq_other = __shfl_xor(kq, 1);
        if (tid == 0) ws[b * 8 + p2] = fmaxf(kq, kq_other);

    } else {
        // ================= LINEAR ROLE =================
        const int b = bid - NB * 4;

        if (tid < NDIM) {
            s_v[tid] = v[b * NDIM + tid];
            s_z[tid] = z0[b * NDIM + tid];
        }
        __syncthreads();

        const int sub = tid & 15;   // column chunk
        const int grp = tid >> 4;   // row group
        const float4 vB = *(const float4*)&s_v[sub * 4];
        const float4 zB = *(const float4*)&s_z[sub * 4];
        float lmax = -INFINITY;
        const float* A1b = A1 + (size_t)b * PROWS * NDIM;
        #pragma unroll
        for (int p = 0; p < 8; ++p) {
            const float4 a = *(const float4*)&A1b[(p * 16 + grp) * NDIM + sub * 4];
            float dv = a.x * vB.x + a.y * vB.y + a.z * vB.z + a.w * vB.w;
            float dz = a.x * zB.x + a.y * zB.y + a.z * zB.z + a.w * zB.w;
            #pragma unroll
            for (int m = 8; m >= 1; m >>= 1) {
                dv += __shfl_xor(dv, m);
                dz += __shfl_xor(dz, m);
            }
            if (sub == 0) {
                const float denom = b1[b * PROWS + p * 16 + grp] - dz;  // > 0
                lmax = fmaxf(lmax, dv / denom);
            }
        }
        #pragma unroll
        for (int m = 32; m >= 1; m >>= 1) lmax = fmaxf(lmax, __shfl_xor(lmax, m));
        if (lane == 0) s_lin[w] = lmax;
        __syncthreads();
        if (tid == 0) {
            const float km = fmaxf(fmaxf(s_lin[0], s_lin[1]), fmaxf(s_lin[2], s_lin[3]));
            ws[b * 8 + 4] = fmaxf(km, 0.f);  // relu
        }
    }
}

// out = z0 + min(1/kraw, 1) * v, kraw = max of 5 ws slots per batch.
__global__ __launch_bounds__(256) void finalize_kernel(
    const float* __restrict__ v,
    const float* __restrict__ z0,
    const float* __restrict__ ws,
    float* __restrict__ out)
{
    const int idx = blockIdx.x * 256 + threadIdx.x;  // over B*64
    const int b   = idx >> 6;
    const float k0 = ws[b * 8 + 0];
    const float k1 = ws[b * 8 + 1];
    const float k2 = ws[b * 8 + 2];
    const float k3 = ws[b * 8 + 3];
    const float k4 = ws[b * 8 + 4];
    const float kraw = fmaxf(fmaxf(fmaxf(k0, k1), fmaxf(k2, k3)), k4);
    const float beta = fminf(1.f / kraw, 1.f);  // 1/0 = inf -> 1
    out[idx] = z0[idx] + beta * v[idx];
}

extern "C" void kernel_launch(void* const* d_in, const int* in_sizes, int n_in,
                              void* d_out, int out_size, void* d_ws, size_t ws_size,
                              hipStream_t stream) {
    const float* v  = (const float*)d_in[0];
    const float* A1 = (const float*)d_in[1];
    const float* b1 = (const float*)d_in[2];
    const float* z0 = (const float*)d_in[3];
    const float* P  = (const float*)d_in[4];
    const float* qv = (const float*)d_in[5];
    const float* rr = (const float*)d_in[6];
    float* ws  = (float*)d_ws;   // B*8 floats = 64KB
    float* out = (float*)d_out;

    main_kernel<<<NB * 4 + NB, 256, 0, stream>>>(v, A1, b1, z0, P, qv, rr, ws);
    finalize_kernel<<<(NB * NDIM) / 256, 256, 0, stream>>>(v, z0, ws, out);
}